// Round 3
// baseline (710.546 us; speedup 1.0000x reference)
//
#include <hip/hip_runtime.h>
#include <hip/hip_bf16.h>
#include <math.h>

typedef __bf16 bf16;
typedef __bf16 bf16x8 __attribute__((ext_vector_type(8)));
typedef __bf16 bf16x4 __attribute__((ext_vector_type(4)));
typedef float f32x4 __attribute__((ext_vector_type(4)));

#define NTOK 65536
#define DMODEL 256

// window-order token m -> global token g (the _reverse mapping)
__device__ __forceinline__ int unwin_idx(int m) {
    int widx = m >> 6, t = m & 63;
    int b = widx >> 6, wl = widx & 63;
    return (b << 12) | (((wl >> 3) * 8 + (t >> 3)) << 6) | ((wl & 7) * 8 + (t & 7));
}

// ---------------------------------------------------------------------------
// Fused QKV: seg0 -> qout plain, seg1 -> kout plain, seg2 -> vout win-transposed
// A = win(feat)+pe staged fp32->bf16. 128x128 tile, 4 waves, grid (M/128, 6).
// ---------------------------------------------------------------------------
__global__ __launch_bounds__(256, 2)
void gemm_qkv(const float* __restrict__ Afp, const float* __restrict__ pe,
              const bf16* __restrict__ w0, const bf16* __restrict__ w1,
              const bf16* __restrict__ w2,
              const float* __restrict__ b0, const float* __restrict__ b1,
              const float* __restrict__ b2,
              bf16* __restrict__ qout, bf16* __restrict__ kout,
              bf16* __restrict__ vout)
{
    __shared__ bf16 As[128][40];
    __shared__ bf16 Bs[128][40];
    const int tid = threadIdx.x;
    const int m0 = blockIdx.x * 128, n0 = blockIdx.y * 128;
    const int seg = n0 >> 8;            // 0,1,2 (uniform per block)
    const int nloc0 = n0 & 255;
    const bf16* wseg = seg == 0 ? w0 : (seg == 1 ? w1 : w2);
    const float* bseg = seg == 0 ? b0 : (seg == 1 ? b1 : b2);
    const int lane = tid & 63, w = tid >> 6;
    const int wr = w >> 1, wc = w & 1;
    const int lr = lane & 15, lg = lane >> 4;
    const int r = tid >> 1, cs = (tid & 1) * 16;   // 16 elems/thread

    f32x4 acc[4][4];
    const f32x4 zero = {0.f, 0.f, 0.f, 0.f};
#pragma unroll
    for (int mi = 0; mi < 4; ++mi)
#pragma unroll
        for (int nj = 0; nj < 4; ++nj) acc[mi][nj] = zero;

    const int mrow = m0 + r;
    const int tA = mrow & 63;
    const int gA = unwin_idx(mrow);

    for (int k0 = 0; k0 < 256; k0 += 32) {
        {
            const float4* fs = reinterpret_cast<const float4*>(Afp + (size_t)gA * DMODEL + k0 + cs);
            const float4* ps = reinterpret_cast<const float4*>(pe + tA * DMODEL + k0 + cs);
            bf16* dst = &As[r][cs];
#pragma unroll
            for (int q = 0; q < 4; ++q) {
                float4 a = fs[q], p = ps[q];
                dst[q * 4 + 0] = (bf16)(a.x + p.x);
                dst[q * 4 + 1] = (bf16)(a.y + p.y);
                dst[q * 4 + 2] = (bf16)(a.z + p.z);
                dst[q * 4 + 3] = (bf16)(a.w + p.w);
            }
        }
        {
            const bf16* src = wseg + (size_t)(nloc0 + r) * 256 + k0 + cs;
            *reinterpret_cast<bf16x8*>(&Bs[r][cs])     = *reinterpret_cast<const bf16x8*>(src);
            *reinterpret_cast<bf16x8*>(&Bs[r][cs + 8]) = *reinterpret_cast<const bf16x8*>(src + 8);
        }
        __syncthreads();
        bf16x8 af[4], bfr[4];
#pragma unroll
        for (int mi = 0; mi < 4; ++mi)
            af[mi] = *reinterpret_cast<const bf16x8*>(&As[wr * 64 + mi * 16 + lr][8 * lg]);
#pragma unroll
        for (int nj = 0; nj < 4; ++nj)
            bfr[nj] = *reinterpret_cast<const bf16x8*>(&Bs[wc * 64 + nj * 16 + lr][8 * lg]);
#pragma unroll
        for (int mi = 0; mi < 4; ++mi)
#pragma unroll
            for (int nj = 0; nj < 4; ++nj)
                acc[mi][nj] = __builtin_amdgcn_mfma_f32_16x16x32_bf16(af[mi], bfr[nj], acc[mi][nj], 0, 0, 0);
        __syncthreads();
    }

#pragma unroll
    for (int mi = 0; mi < 4; ++mi) {
#pragma unroll
        for (int nj = 0; nj < 4; ++nj) {
            int cl = nloc0 + wc * 64 + nj * 16 + lr;   // col within segment (0..255)
            float bv = bseg[cl];
#pragma unroll
            for (int i = 0; i < 4; ++i) {
                int row = m0 + wr * 64 + mi * 16 + lg * 4 + i;
                bf16 o = (bf16)(acc[mi][nj][i] + bv);
                if (seg == 0) {
                    qout[(size_t)row * 256 + cl] = o;
                } else if (seg == 1) {
                    kout[(size_t)row * 256 + cl] = o;
                } else {
                    int widx = row >> 6, tt = row & 63;
                    vout[((size_t)widx * 256 + cl) * 64 + tt] = o;
                }
            }
        }
    }
}

// ---------------------------------------------------------------------------
// FFN1: C[M,N] = gelu(A[M,K] @ W[N,K]^T + bias), bf16 in/out, 128x128 tile
// ---------------------------------------------------------------------------
__global__ __launch_bounds__(256, 2)
void gemm_ffn1(const bf16* __restrict__ Abf, const bf16* __restrict__ Wt,
               const float* __restrict__ bias, bf16* __restrict__ C,
               int N, int K)
{
    __shared__ bf16 As[128][40];
    __shared__ bf16 Bs[128][40];
    const int tid = threadIdx.x;
    const int m0 = blockIdx.x * 128, n0 = blockIdx.y * 128;
    const int lane = tid & 63, w = tid >> 6;
    const int wr = w >> 1, wc = w & 1;
    const int lr = lane & 15, lg = lane >> 4;
    const int r = tid >> 1, cs = (tid & 1) * 16;   // 16 elems/thread

    f32x4 acc[4][4];
    const f32x4 zero = {0.f, 0.f, 0.f, 0.f};
#pragma unroll
    for (int mi = 0; mi < 4; ++mi)
#pragma unroll
        for (int nj = 0; nj < 4; ++nj) acc[mi][nj] = zero;

    for (int k0 = 0; k0 < K; k0 += 32) {
        {
            const bf16* src = Abf + (size_t)(m0 + r) * K + k0 + cs;
            *reinterpret_cast<bf16x8*>(&As[r][cs])     = *reinterpret_cast<const bf16x8*>(src);
            *reinterpret_cast<bf16x8*>(&As[r][cs + 8]) = *reinterpret_cast<const bf16x8*>(src + 8);
        }
        {
            const bf16* src = Wt + (size_t)(n0 + r) * K + k0 + cs;
            *reinterpret_cast<bf16x8*>(&Bs[r][cs])     = *reinterpret_cast<const bf16x8*>(src);
            *reinterpret_cast<bf16x8*>(&Bs[r][cs + 8]) = *reinterpret_cast<const bf16x8*>(src + 8);
        }
        __syncthreads();
        bf16x8 af[4], bfr[4];
#pragma unroll
        for (int mi = 0; mi < 4; ++mi)
            af[mi] = *reinterpret_cast<const bf16x8*>(&As[wr * 64 + mi * 16 + lr][8 * lg]);
#pragma unroll
        for (int nj = 0; nj < 4; ++nj)
            bfr[nj] = *reinterpret_cast<const bf16x8*>(&Bs[wc * 64 + nj * 16 + lr][8 * lg]);
#pragma unroll
        for (int mi = 0; mi < 4; ++mi)
#pragma unroll
            for (int nj = 0; nj < 4; ++nj)
                acc[mi][nj] = __builtin_amdgcn_mfma_f32_16x16x32_bf16(af[mi], bfr[nj], acc[mi][nj], 0, 0, 0);
        __syncthreads();
    }

#pragma unroll
    for (int mi = 0; mi < 4; ++mi) {
#pragma unroll
        for (int nj = 0; nj < 4; ++nj) {
            int col = n0 + wc * 64 + nj * 16 + lr;
            float bv = bias[col];
#pragma unroll
            for (int i = 0; i < 4; ++i) {
                int row = m0 + wr * 64 + mi * 16 + lg * 4 + i;
                float v = acc[mi][nj][i] + bv;
                v = 0.5f * v * (1.0f + erff(v * 0.70710678118654752f));
                C[(size_t)row * N + col] = (bf16)v;
            }
        }
    }
}

// ---------------------------------------------------------------------------
// Fused GEMM + residual + LayerNorm.
// C = LN(A @ W^T + bias + res) * gamma + beta
// Tile 128 rows x 256 cols (full row in block), 8 waves (2 row x 4 col groups).
// ---------------------------------------------------------------------------
template<int UNWIN, int WRITE_BF>
__global__ __launch_bounds__(512, 2)
void gemm_ln(const bf16* __restrict__ Abf, const bf16* __restrict__ Wt,
             const float* __restrict__ bias, const float* __restrict__ res,
             const float* __restrict__ gamma, const float* __restrict__ beta,
             float* __restrict__ outf, bf16* __restrict__ outb, int K)
{
    __shared__ bf16 As[128][40];
    __shared__ bf16 Bs[256][40];
    __shared__ float redS[4][128];
    __shared__ float redQ[4][128];
    const int tid = threadIdx.x;
    const int m0 = blockIdx.x * 128;
    const int lane = tid & 63, w = tid >> 6;
    const int wr = w >> 2, wc = w & 3;          // 2 x 4 wave grid
    const int lr = lane & 15, lg = lane >> 4;
    const int rA = tid >> 2, csA = (tid & 3) * 8;    // A: 8 elems/thread (full)
    const int rB = tid >> 1, csB = (tid & 1) * 16;   // B: 16 elems/thread (full)

    f32x4 acc[4][4];
    const f32x4 zero = {0.f, 0.f, 0.f, 0.f};
#pragma unroll
    for (int mi = 0; mi < 4; ++mi)
#pragma unroll
        for (int nj = 0; nj < 4; ++nj) acc[mi][nj] = zero;

    for (int k0 = 0; k0 < K; k0 += 32) {
        *reinterpret_cast<bf16x8*>(&As[rA][csA]) =
            *reinterpret_cast<const bf16x8*>(Abf + (size_t)(m0 + rA) * K + k0 + csA);
        {
            const bf16* src = Wt + (size_t)rB * K + k0 + csB;
            *reinterpret_cast<bf16x8*>(&Bs[rB][csB])     = *reinterpret_cast<const bf16x8*>(src);
            *reinterpret_cast<bf16x8*>(&Bs[rB][csB + 8]) = *reinterpret_cast<const bf16x8*>(src + 8);
        }
        __syncthreads();
        bf16x8 af[4], bfr[4];
#pragma unroll
        for (int mi = 0; mi < 4; ++mi)
            af[mi] = *reinterpret_cast<const bf16x8*>(&As[wr * 64 + mi * 16 + lr][8 * lg]);
#pragma unroll
        for (int nj = 0; nj < 4; ++nj)
            bfr[nj] = *reinterpret_cast<const bf16x8*>(&Bs[wc * 64 + nj * 16 + lr][8 * lg]);
#pragma unroll
        for (int mi = 0; mi < 4; ++mi)
#pragma unroll
            for (int nj = 0; nj < 4; ++nj)
                acc[mi][nj] = __builtin_amdgcn_mfma_f32_16x16x32_bf16(af[mi], bfr[nj], acc[mi][nj], 0, 0, 0);
        __syncthreads();
    }

    // epilogue: v = acc + bias + res ; per-row mean/var over 256 cols
    float bsv[4], gv[4], bvv[4];
    int cols[4];
#pragma unroll
    for (int nj = 0; nj < 4; ++nj) {
        cols[nj] = wc * 64 + nj * 16 + lr;
        bsv[nj] = bias[cols[nj]];
        gv[nj] = gamma[cols[nj]];
        bvv[nj] = beta[cols[nj]];
    }
    int grow[4][4];
#pragma unroll
    for (int mi = 0; mi < 4; ++mi)
#pragma unroll
        for (int i = 0; i < 4; ++i) {
            int rloc = wr * 64 + mi * 16 + lg * 4 + i;
            int m = m0 + rloc;
            grow[mi][i] = UNWIN ? unwin_idx(m) : m;
        }

#pragma unroll
    for (int mi = 0; mi < 4; ++mi)
#pragma unroll
        for (int i = 0; i < 4; ++i) {
            const float* rp = res + (size_t)grow[mi][i] * 256;
            float ls = 0.f, lq = 0.f;
#pragma unroll
            for (int nj = 0; nj < 4; ++nj) {
                float v = acc[mi][nj][i] + bsv[nj] + rp[cols[nj]];
                acc[mi][nj][i] = v;
                ls += v;
                lq += v * v;
            }
            ls += __shfl_xor(ls, 1); lq += __shfl_xor(lq, 1);
            ls += __shfl_xor(ls, 2); lq += __shfl_xor(lq, 2);
            ls += __shfl_xor(ls, 4); lq += __shfl_xor(lq, 4);
            ls += __shfl_xor(ls, 8); lq += __shfl_xor(lq, 8);
            if (lr == 0) {
                int rloc = wr * 64 + mi * 16 + lg * 4 + i;
                redS[wc][rloc] = ls;
                redQ[wc][rloc] = lq;
            }
        }
    __syncthreads();

#pragma unroll
    for (int mi = 0; mi < 4; ++mi)
#pragma unroll
        for (int i = 0; i < 4; ++i) {
            int rloc = wr * 64 + mi * 16 + lg * 4 + i;
            float S = redS[0][rloc] + redS[1][rloc] + redS[2][rloc] + redS[3][rloc];
            float Q = redQ[0][rloc] + redQ[1][rloc] + redQ[2][rloc] + redQ[3][rloc];
            float mean = S * (1.f / 256.f);
            float var = Q * (1.f / 256.f) - mean * mean;
            float rstd = rsqrtf(var + 1e-5f);
            float* op = outf + (size_t)grow[mi][i] * 256;
            bf16* ob = WRITE_BF ? outb + (size_t)grow[mi][i] * 256 : nullptr;
#pragma unroll
            for (int nj = 0; nj < 4; ++nj) {
                float o = (acc[mi][nj][i] - mean) * rstd * gv[nj] + bvv[nj];
                op[cols[nj]] = o;
                if (WRITE_BF) ob[cols[nj]] = (bf16)o;
            }
        }
}

// ---------------------------------------------------------------------------
// Attention: one wave per (window, head). obuf may alias qbuf.
// ---------------------------------------------------------------------------
__global__ __launch_bounds__(64)
void attn_win(const bf16* qbuf, const bf16* __restrict__ kbuf,
              const bf16* __restrict__ vtbuf, bf16* obuf)
{
    __shared__ bf16 Qs[64][72];  // reused for P after S-phase
    __shared__ bf16 Ks[64][72];
    __shared__ bf16 Vs[64][72];  // Vt: row=d_local, col=key
    const int lane = threadIdx.x;
    const int widx = blockIdx.x >> 2, head = blockIdx.x & 3;
    const int lr = lane & 15, lg = lane >> 4;
    const int rr = lane >> 3, jj = lane & 7;

#pragma unroll
    for (int i = 0; i < 8; ++i) {
        int row = i * 8 + rr;
        *reinterpret_cast<bf16x8*>(&Qs[row][jj * 8]) =
            *reinterpret_cast<const bf16x8*>(qbuf + ((size_t)widx * 64 + row) * 256 + head * 64 + jj * 8);
        *reinterpret_cast<bf16x8*>(&Ks[row][jj * 8]) =
            *reinterpret_cast<const bf16x8*>(kbuf + ((size_t)widx * 64 + row) * 256 + head * 64 + jj * 8);
        *reinterpret_cast<bf16x8*>(&Vs[row][jj * 8]) =
            *reinterpret_cast<const bf16x8*>(vtbuf + (size_t)widx * 16384 + (head * 64 + row) * 64 + jj * 8);
    }
    __syncthreads();

    const f32x4 zero = {0.f, 0.f, 0.f, 0.f};
    f32x4 sacc[4][4];
#pragma unroll
    for (int mi = 0; mi < 4; ++mi)
#pragma unroll
        for (int nj = 0; nj < 4; ++nj) sacc[mi][nj] = zero;

#pragma unroll
    for (int k0 = 0; k0 < 64; k0 += 32) {
        bf16x8 af[4], bfr[4];
#pragma unroll
        for (int mi = 0; mi < 4; ++mi)
            af[mi] = *reinterpret_cast<const bf16x8*>(&Qs[mi * 16 + lr][k0 + 8 * lg]);
#pragma unroll
        for (int nj = 0; nj < 4; ++nj)
            bfr[nj] = *reinterpret_cast<const bf16x8*>(&Ks[nj * 16 + lr][k0 + 8 * lg]);
#pragma unroll
        for (int mi = 0; mi < 4; ++mi)
#pragma unroll
            for (int nj = 0; nj < 4; ++nj)
                sacc[mi][nj] = __builtin_amdgcn_mfma_f32_16x16x32_bf16(af[mi], bfr[nj], sacc[mi][nj], 0, 0, 0);
    }

    const float c = 0.125f * 1.4426950408889634f;  // log2(e)/sqrt(dh)
    float rmax[4][4], rsum[4][4];
#pragma unroll
    for (int mi = 0; mi < 4; ++mi)
#pragma unroll
        for (int i = 0; i < 4; ++i) {
            float m = fmaxf(fmaxf(sacc[mi][0][i], sacc[mi][1][i]), fmaxf(sacc[mi][2][i], sacc[mi][3][i]));
            m = fmaxf(m, __shfl_xor(m, 1));
            m = fmaxf(m, __shfl_xor(m, 2));
            m = fmaxf(m, __shfl_xor(m, 4));
            m = fmaxf(m, __shfl_xor(m, 8));
            rmax[mi][i] = m;
        }
#pragma unroll
    for (int mi = 0; mi < 4; ++mi)
#pragma unroll
        for (int nj = 0; nj < 4; ++nj)
#pragma unroll
            for (int i = 0; i < 4; ++i)
                sacc[mi][nj][i] = exp2f((sacc[mi][nj][i] - rmax[mi][i]) * c);
#pragma unroll
    for (int mi = 0; mi < 4; ++mi)
#pragma unroll
        for (int i = 0; i < 4; ++i) {
            float s = sacc[mi][0][i] + sacc[mi][1][i] + sacc[mi][2][i] + sacc[mi][3][i];
            s += __shfl_xor(s, 1);
            s += __shfl_xor(s, 2);
            s += __shfl_xor(s, 4);
            s += __shfl_xor(s, 8);
            rsum[mi][i] = s;
        }
    __syncthreads();  // Qs reads done; reuse as P
#pragma unroll
    for (int mi = 0; mi < 4; ++mi)
#pragma unroll
        for (int nj = 0; nj < 4; ++nj)
#pragma unroll
            for (int i = 0; i < 4; ++i)
                Qs[mi * 16 + lg * 4 + i][nj * 16 + lr] = (bf16)sacc[mi][nj][i];
    __syncthreads();

    f32x4 oacc[4][4];
#pragma unroll
    for (int mi = 0; mi < 4; ++mi)
#pragma unroll
        for (int nj = 0; nj < 4; ++nj) oacc[mi][nj] = zero;
#pragma unroll
    for (int k0 = 0; k0 < 64; k0 += 32) {
        bf16x8 af[4], bfr[4];
#pragma unroll
        for (int mi = 0; mi < 4; ++mi)
            af[mi] = *reinterpret_cast<const bf16x8*>(&Qs[mi * 16 + lr][k0 + 8 * lg]);
#pragma unroll
        for (int nj = 0; nj < 4; ++nj)
            bfr[nj] = *reinterpret_cast<const bf16x8*>(&Vs[nj * 16 + lr][k0 + 8 * lg]);
#pragma unroll
        for (int mi = 0; mi < 4; ++mi)
#pragma unroll
            for (int nj = 0; nj < 4; ++nj)
                oacc[mi][nj] = __builtin_amdgcn_mfma_f32_16x16x32_bf16(af[mi], bfr[nj], oacc[mi][nj], 0, 0, 0);
    }
#pragma unroll
    for (int mi = 0; mi < 4; ++mi)
#pragma unroll
        for (int i = 0; i < 4; ++i) {
            float inv = 1.0f / rsum[mi][i];
            int row = mi * 16 + lg * 4 + i;
#pragma unroll
            for (int nj = 0; nj < 4; ++nj) {
                int col = nj * 16 + lr;
                obuf[((size_t)widx * 64 + row) * 256 + head * 64 + col] = (bf16)(oacc[mi][nj][i] * inv);
            }
        }
}

__global__ void cvt_bf16(const float* __restrict__ s, bf16* __restrict__ d, int n)
{
    int i = blockIdx.x * 256 + threadIdx.x;
    if (i < n) d[i] = (bf16)s[i];
}

extern "C" void kernel_launch(void* const* d_in, const int* in_sizes, int n_in,
                              void* d_out, int out_size, void* d_ws, size_t ws_size,
                              hipStream_t stream)
{
    const float* feat_A       = (const float*)d_in[0];
    const float* feat_B       = (const float*)d_in[1];
    const float* pe           = (const float*)d_in[2];
    const float* qkv_w_A      = (const float*)d_in[3];
    const float* qkv_b_A      = (const float*)d_in[4];
    const float* out_w_A      = (const float*)d_in[5];
    const float* out_b_A      = (const float*)d_in[6];
    const float* norm_g_A     = (const float*)d_in[7];
    const float* norm_b_A     = (const float*)d_in[8];
    const float* ffn_norm_g_A = (const float*)d_in[9];
    const float* ffn_norm_b_A = (const float*)d_in[10];
    const float* ffn_w1_A     = (const float*)d_in[11];
    const float* ffn_b1_A     = (const float*)d_in[12];
    const float* ffn_w2_A     = (const float*)d_in[13];
    const float* ffn_b2_A     = (const float*)d_in[14];
    const float* qkv_w_B      = (const float*)d_in[15];
    const float* qkv_b_B      = (const float*)d_in[16];
    const float* out_w_B      = (const float*)d_in[17];
    const float* out_b_B      = (const float*)d_in[18];
    const float* norm_g_B     = (const float*)d_in[19];
    const float* norm_b_B     = (const float*)d_in[20];
    const float* ffn_norm_g_B = (const float*)d_in[21];
    const float* ffn_norm_b_B = (const float*)d_in[22];
    const float* ffn_w1_B     = (const float*)d_in[23];
    const float* ffn_b1_B     = (const float*)d_in[24];
    const float* ffn_w2_B     = (const float*)d_in[25];
    const float* ffn_b2_B     = (const float*)d_in[26];

    char* ws = (char*)d_ws;
    const size_t BFE = (size_t)NTOK * DMODEL;      // 16,777,216 elems
    const size_t BFB = BFE * 2;                    // bytes per bf16 activation buffer

    bf16* Wb = (bf16*)ws;                          // 2 MB of bf16 weights
    size_t off = 2u * 1024 * 1024;
    bf16* qA = (bf16*)(ws + off); off += BFB;
    bf16* kA = (bf16*)(ws + off); off += BFB;
    bf16* vA = (bf16*)(ws + off); off += BFB;
    bf16* qB = (bf16*)(ws + off); off += BFB;
    bf16* kB = (bf16*)(ws + off); off += BFB;
    bf16* vB = (bf16*)(ws + off); off += BFB;
    bf16* hb = (bf16*)(ws + off); off += BFB * 2;  // 65536 x 512
    bf16* tb = (bf16*)(ws + off); off += BFB;
    // reuse after attention consumes k/v:
    float* y1A = (float*)kA;   // spans kA+vA (67 MB)
    float* y1B = (float*)kB;   // spans kB+vB

    bf16* w_qkvA = Wb + 0;
    bf16* w_outA = Wb + 196608;
    bf16* w_f1A  = Wb + 262144;
    bf16* w_f2A  = Wb + 393216;
    bf16* w_qkvB = Wb + 524288;
    bf16* w_outB = Wb + 720896;
    bf16* w_f1B  = Wb + 786432;
    bf16* w_f2B  = Wb + 917504;

    cvt_bf16<<<(196608 + 255) / 256, 256, 0, stream>>>(qkv_w_A, w_qkvA, 196608);
    cvt_bf16<<<(65536 + 255) / 256, 256, 0, stream>>>(out_w_A, w_outA, 65536);
    cvt_bf16<<<(131072 + 255) / 256, 256, 0, stream>>>(ffn_w1_A, w_f1A, 131072);
    cvt_bf16<<<(131072 + 255) / 256, 256, 0, stream>>>(ffn_w2_A, w_f2A, 131072);
    cvt_bf16<<<(196608 + 255) / 256, 256, 0, stream>>>(qkv_w_B, w_qkvB, 196608);
    cvt_bf16<<<(65536 + 255) / 256, 256, 0, stream>>>(out_w_B, w_outB, 65536);
    cvt_bf16<<<(131072 + 255) / 256, 256, 0, stream>>>(ffn_w1_B, w_f1B, 131072);
    cvt_bf16<<<(131072 + 255) / 256, 256, 0, stream>>>(ffn_w2_B, w_f2B, 131072);

    dim3 blk(256);
    dim3 gq(512, 6), g512(512, 4);

    // Fused QKV: feat_A pass -> qA (wA[0]), kB (wB[1]), vB (wB[2])
    gemm_qkv<<<gq, blk, 0, stream>>>(feat_A, pe,
                                     w_qkvA, w_qkvB + 65536, w_qkvB + 131072,
                                     qkv_b_A, qkv_b_B + 256, qkv_b_B + 512,
                                     qA, kB, vB);
    //            feat_B pass -> qB (wB[0]), kA (wA[1]), vA (wA[2])
    gemm_qkv<<<gq, blk, 0, stream>>>(feat_B, pe,
                                     w_qkvB, w_qkvA + 65536, w_qkvA + 131072,
                                     qkv_b_B, qkv_b_A + 256, qkv_b_A + 512,
                                     qB, kA, vA);

    attn_win<<<4096, 64, 0, stream>>>(qA, kA, vA, qA);
    attn_win<<<4096, 64, 0, stream>>>(qB, kB, vB, qB);

    // stream A: out-proj+LN1 -> FFN1 -> FFN2+LN2
    gemm_ln<1, 1><<<512, 512, 0, stream>>>(qA, w_outA, out_b_A, feat_A,
                                           norm_g_A, norm_b_A, y1A, tb, 256);
    gemm_ffn1<<<g512, blk, 0, stream>>>(tb, w_f1A, ffn_b1_A, hb, 512, 256);
    gemm_ln<0, 0><<<512, 512, 0, stream>>>(hb, w_f2A, ffn_b2_A, y1A,
                                           ffn_norm_g_A, ffn_norm_b_A,
                                           (float*)d_out, nullptr, 512);

    // stream B
    gemm_ln<1, 1><<<512, 512, 0, stream>>>(qB, w_outB, out_b_B, feat_B,
                                           norm_g_B, norm_b_B, y1B, tb, 256);
    gemm_ffn1<<<g512, blk, 0, stream>>>(tb, w_f1B, ffn_b1_B, hb, 512, 256);
    gemm_ln<0, 0><<<512, 512, 0, stream>>>(hb, w_f2B, ffn_b2_B, y1B,
                                           ffn_norm_g_B, ffn_norm_b_B,
                                           (float*)d_out + BFE, nullptr, 512);
}

// Round 4
// 603.095 us; speedup vs baseline: 1.1782x; 1.1782x over previous
//
#include <hip/hip_runtime.h>
#include <hip/hip_bf16.h>
#include <math.h>

typedef __bf16 bf16;
typedef __bf16 bf16x8 __attribute__((ext_vector_type(8)));
typedef __bf16 bf16x4 __attribute__((ext_vector_type(4)));
typedef float f32x4 __attribute__((ext_vector_type(4)));

#define NTOK 65536
#define DMODEL 256

// async global->LDS, 16B per lane; LDS dest = wave-uniform base + lane*16
#define GL16(g, l) __builtin_amdgcn_global_load_lds( \
    (const __attribute__((address_space(1))) void*)(g), \
    (__attribute__((address_space(3))) void*)(l), 16, 0, 0)

// window-order token m -> global token g (the _reverse mapping)
__device__ __forceinline__ int unwin_idx(int m) {
    int widx = m >> 6, t = m & 63;
    int b = widx >> 6, wl = widx & 63;
    return (b << 12) | (((wl >> 3) * 8 + (t >> 3)) << 6) | ((wl & 7) * 8 + (t & 7));
}

__device__ __forceinline__ float gelu_fast(float x) {
    float z = 0.7978845608f * (x + 0.044715f * x * x * x);
    float e = __expf(2.f * z);
    float t = (e - 1.f) / (e + 1.f);
    return 0.5f * x * (1.f + t);
}

// ---------------------------------------------------------------------------
// prep: aw[m][c] = bf16(feat[unwin(m)][c] + pe[m&63][c]); grid (8192, 2)
// ---------------------------------------------------------------------------
__global__ __launch_bounds__(256)
void prep_win(const float* __restrict__ fA, const float* __restrict__ fB,
              const float* __restrict__ pe,
              bf16* __restrict__ awA, bf16* __restrict__ awB)
{
    const float* f = blockIdx.y ? fB : fA;
    bf16* aw = blockIdx.y ? awB : awA;
    int m = blockIdx.x * 8 + (threadIdx.x >> 5);
    int c = (threadIdx.x & 31) * 8;
    int g = unwin_idx(m), t = m & 63;
    const float4* fs = reinterpret_cast<const float4*>(f + (size_t)g * 256 + c);
    const float4* ps = reinterpret_cast<const float4*>(pe + t * 256 + c);
    float4 a0 = fs[0], a1 = fs[1], p0 = ps[0], p1 = ps[1];
    bf16x8 o;
    o[0] = (bf16)(a0.x + p0.x); o[1] = (bf16)(a0.y + p0.y);
    o[2] = (bf16)(a0.z + p0.z); o[3] = (bf16)(a0.w + p0.w);
    o[4] = (bf16)(a1.x + p1.x); o[5] = (bf16)(a1.y + p1.y);
    o[6] = (bf16)(a1.z + p1.z); o[7] = (bf16)(a1.w + p1.w);
    *reinterpret_cast<bf16x8*>(aw + (size_t)m * 256 + c) = o;
}

// ---------------------------------------------------------------------------
// weight convert: all 8 fp32 weight arrays -> one bf16 pool (fixed layout)
// ---------------------------------------------------------------------------
__global__ __launch_bounds__(256)
void cvt8(const float* __restrict__ s0, const float* __restrict__ s1,
          const float* __restrict__ s2, const float* __restrict__ s3,
          const float* __restrict__ s4, const float* __restrict__ s5,
          const float* __restrict__ s6, const float* __restrict__ s7,
          bf16* __restrict__ d)
{
    int idx = (blockIdx.x * 256 + threadIdx.x) * 4;
    const float* s; int off;
    if      (idx < 196608) { s = s0; off = 0; }
    else if (idx < 262144) { s = s1; off = 196608; }
    else if (idx < 393216) { s = s2; off = 262144; }
    else if (idx < 524288) { s = s3; off = 393216; }
    else if (idx < 720896) { s = s4; off = 524288; }
    else if (idx < 786432) { s = s5; off = 720896; }
    else if (idx < 917504) { s = s6; off = 786432; }
    else                   { s = s7; off = 917504; }
    float4 v = *reinterpret_cast<const float4*>(s + (idx - off));
    bf16x4 o; o[0] = (bf16)v.x; o[1] = (bf16)v.y; o[2] = (bf16)v.z; o[3] = (bf16)v.w;
    *reinterpret_cast<bf16x4*>(d + idx) = o;
}

// ---------------------------------------------------------------------------
// QKV GEMM: A[M][256] bf16 (window order), N=768 via 3 weight segs.
// seg0->qout plain, seg1->kout plain, seg2->vout per-window transposed.
// 128x128 tile, 4 waves, global_load_lds staging, grid 512*6 (n-fastest).
// ---------------------------------------------------------------------------
__global__ __launch_bounds__(256, 2)
void gemm_qkv2(const bf16* __restrict__ A,
               const bf16* __restrict__ w0, const bf16* __restrict__ w1,
               const bf16* __restrict__ w2,
               const float* __restrict__ b0, const float* __restrict__ b1,
               const float* __restrict__ b2,
               bf16* __restrict__ qout, bf16* __restrict__ kout,
               bf16* __restrict__ vout)
{
    __shared__ bf16 As[128 * 32];
    __shared__ bf16 Bs[128 * 32];
    const int tid = threadIdx.x;
    const int bx = blockIdx.x;
    const int nb = bx % 6, mb = bx / 6;       // n-fastest: A-tile L2 reuse
    const int m0 = mb * 128;
    const int seg = nb >> 1, nl0 = (nb & 1) * 128;
    const bf16* W = seg == 0 ? w0 : (seg == 1 ? w1 : w2);
    const float* bia = seg == 0 ? b0 : (seg == 1 ? b1 : b2);
    const int lane = tid & 63, w = tid >> 6;
    const int wr = w >> 1, wc = w & 1;
    const int lr = lane & 15, lg = lane >> 4;
    const int srow = tid >> 2, scol = (tid & 3) * 8;

    const bf16* Ag = A + (size_t)(m0 + srow) * 256 + scol;
    const bf16* Bg = W + (size_t)(nl0 + srow) * 256 + scol;
    bf16* lA = &As[tid * 8];
    bf16* lB = &Bs[tid * 8];

    f32x4 acc[4][4];
    const f32x4 zero = {0.f, 0.f, 0.f, 0.f};
#pragma unroll
    for (int mi = 0; mi < 4; ++mi)
#pragma unroll
        for (int nj = 0; nj < 4; ++nj) acc[mi][nj] = zero;

    for (int k0 = 0; k0 < 256; k0 += 32) {
        GL16(Ag + k0, lA);
        GL16(Ag + 64 * 256 + k0, lA + 2048);
        GL16(Bg + k0, lB);
        GL16(Bg + 64 * 256 + k0, lB + 2048);
        __syncthreads();
        bf16x8 af[4], bfr[4];
#pragma unroll
        for (int mi = 0; mi < 4; ++mi)
            af[mi] = *reinterpret_cast<const bf16x8*>(&As[(wr * 64 + mi * 16 + lr) * 32 + lg * 8]);
#pragma unroll
        for (int nj = 0; nj < 4; ++nj)
            bfr[nj] = *reinterpret_cast<const bf16x8*>(&Bs[(wc * 64 + nj * 16 + lr) * 32 + lg * 8]);
#pragma unroll
        for (int mi = 0; mi < 4; ++mi)
#pragma unroll
            for (int nj = 0; nj < 4; ++nj)
                acc[mi][nj] = __builtin_amdgcn_mfma_f32_16x16x32_bf16(af[mi], bfr[nj], acc[mi][nj], 0, 0, 0);
        __syncthreads();
    }

#pragma unroll
    for (int nj = 0; nj < 4; ++nj) {
        int cl = nl0 + wc * 64 + nj * 16 + lr;
        float bv = bia[cl];
#pragma unroll
        for (int mi = 0; mi < 4; ++mi)
#pragma unroll
            for (int i = 0; i < 4; ++i) {
                int row = m0 + wr * 64 + mi * 16 + lg * 4 + i;
                bf16 o = (bf16)(acc[mi][nj][i] + bv);
                if (seg == 0) {
                    qout[(size_t)row * 256 + cl] = o;
                } else if (seg == 1) {
                    kout[(size_t)row * 256 + cl] = o;
                } else {
                    int widx = row >> 6, tt = row & 63;
                    vout[((size_t)widx * 256 + cl) * 64 + tt] = o;
                }
            }
    }
}

// ---------------------------------------------------------------------------
// FFN1: C[M,512] = gelu(A[M,256] @ W[512,256]^T + b); grid 512*4 (n-fastest)
// ---------------------------------------------------------------------------
__global__ __launch_bounds__(256, 2)
void gemm_gelu(const bf16* __restrict__ A, const bf16* __restrict__ W,
               const float* __restrict__ bias, bf16* __restrict__ C)
{
    __shared__ bf16 As[128 * 32];
    __shared__ bf16 Bs[128 * 32];
    const int tid = threadIdx.x;
    const int bx = blockIdx.x;
    const int nb = bx & 3, mb = bx >> 2;
    const int m0 = mb * 128, n0 = nb * 128;
    const int lane = tid & 63, w = tid >> 6;
    const int wr = w >> 1, wc = w & 1;
    const int lr = lane & 15, lg = lane >> 4;
    const int srow = tid >> 2, scol = (tid & 3) * 8;

    const bf16* Ag = A + (size_t)(m0 + srow) * 256 + scol;
    const bf16* Bg = W + (size_t)(n0 + srow) * 256 + scol;
    bf16* lA = &As[tid * 8];
    bf16* lB = &Bs[tid * 8];

    f32x4 acc[4][4];
    const f32x4 zero = {0.f, 0.f, 0.f, 0.f};
#pragma unroll
    for (int mi = 0; mi < 4; ++mi)
#pragma unroll
        for (int nj = 0; nj < 4; ++nj) acc[mi][nj] = zero;

    for (int k0 = 0; k0 < 256; k0 += 32) {
        GL16(Ag + k0, lA);
        GL16(Ag + 64 * 256 + k0, lA + 2048);
        GL16(Bg + k0, lB);
        GL16(Bg + 64 * 256 + k0, lB + 2048);
        __syncthreads();
        bf16x8 af[4], bfr[4];
#pragma unroll
        for (int mi = 0; mi < 4; ++mi)
            af[mi] = *reinterpret_cast<const bf16x8*>(&As[(wr * 64 + mi * 16 + lr) * 32 + lg * 8]);
#pragma unroll
        for (int nj = 0; nj < 4; ++nj)
            bfr[nj] = *reinterpret_cast<const bf16x8*>(&Bs[(wc * 64 + nj * 16 + lr) * 32 + lg * 8]);
#pragma unroll
        for (int mi = 0; mi < 4; ++mi)
#pragma unroll
            for (int nj = 0; nj < 4; ++nj)
                acc[mi][nj] = __builtin_amdgcn_mfma_f32_16x16x32_bf16(af[mi], bfr[nj], acc[mi][nj], 0, 0, 0);
        __syncthreads();
    }

#pragma unroll
    for (int nj = 0; nj < 4; ++nj) {
        int col = n0 + wc * 64 + nj * 16 + lr;
        float bv = bias[col];
#pragma unroll
        for (int mi = 0; mi < 4; ++mi)
#pragma unroll
            for (int i = 0; i < 4; ++i) {
                int row = m0 + wr * 64 + mi * 16 + lg * 4 + i;
                float v = gelu_fast(acc[mi][nj][i] + bv);
                C[(size_t)row * 512 + col] = (bf16)v;
            }
    }
}

// ---------------------------------------------------------------------------
// GEMM + residual + LayerNorm. C = LN(A@W^T + b + res)*g + beta
// 128x256 tile (full row), 8 waves. UNWIN=1: res=fp32 feat via unwin, out=bf16.
// UNWIN=0: res=bf16, out=fp32.
// ---------------------------------------------------------------------------
template<int UNWIN>
__global__ __launch_bounds__(512, 2)
void gemm_lnr(const bf16* __restrict__ A, const bf16* __restrict__ W,
              const float* __restrict__ bias,
              const float* __restrict__ resf, const bf16* __restrict__ resb,
              const float* __restrict__ gamma, const float* __restrict__ beta,
              float* __restrict__ outf, bf16* __restrict__ outb, int K)
{
    __shared__ bf16 As[128 * 32];
    __shared__ bf16 Bs[256 * 32];
    __shared__ float redS[4][128];
    __shared__ float redQ[4][128];
    const int tid = threadIdx.x;
    const int m0 = blockIdx.x * 128;
    const int lane = tid & 63, w = tid >> 6;
    const int wr = w >> 2, wc = w & 3;
    const int lr = lane & 15, lg = lane >> 4;
    const int srow = tid >> 2, scol = (tid & 3) * 8;

    const bf16* Ag = A + (size_t)(m0 + srow) * K + scol;
    const bf16* Bg0 = W + (size_t)srow * K + scol;
    const bf16* Bg1 = W + (size_t)(128 + srow) * K + scol;
    bf16* lA = &As[tid * 8];
    bf16* lB = &Bs[tid * 8];

    f32x4 acc[4][4];
    const f32x4 zero = {0.f, 0.f, 0.f, 0.f};
#pragma unroll
    for (int mi = 0; mi < 4; ++mi)
#pragma unroll
        for (int nj = 0; nj < 4; ++nj) acc[mi][nj] = zero;

    for (int k0 = 0; k0 < K; k0 += 32) {
        GL16(Ag + k0, lA);
        GL16(Bg0 + k0, lB);
        GL16(Bg1 + k0, lB + 4096);
        __syncthreads();
        bf16x8 af[4], bfr[4];
#pragma unroll
        for (int mi = 0; mi < 4; ++mi)
            af[mi] = *reinterpret_cast<const bf16x8*>(&As[(wr * 64 + mi * 16 + lr) * 32 + lg * 8]);
#pragma unroll
        for (int nj = 0; nj < 4; ++nj)
            bfr[nj] = *reinterpret_cast<const bf16x8*>(&Bs[(wc * 64 + nj * 16 + lr) * 32 + lg * 8]);
#pragma unroll
        for (int mi = 0; mi < 4; ++mi)
#pragma unroll
            for (int nj = 0; nj < 4; ++nj)
                acc[mi][nj] = __builtin_amdgcn_mfma_f32_16x16x32_bf16(af[mi], bfr[nj], acc[mi][nj], 0, 0, 0);
        __syncthreads();
    }

    float bsv[4], gv[4], bvv[4];
    int cols[4];
#pragma unroll
    for (int nj = 0; nj < 4; ++nj) {
        cols[nj] = wc * 64 + nj * 16 + lr;
        bsv[nj] = bias[cols[nj]];
        gv[nj] = gamma[cols[nj]];
        bvv[nj] = beta[cols[nj]];
    }
    int grow[4][4];
#pragma unroll
    for (int mi = 0; mi < 4; ++mi)
#pragma unroll
        for (int i = 0; i < 4; ++i) {
            int m = m0 + wr * 64 + mi * 16 + lg * 4 + i;
            grow[mi][i] = UNWIN ? unwin_idx(m) : m;
        }

#pragma unroll
    for (int mi = 0; mi < 4; ++mi)
#pragma unroll
        for (int i = 0; i < 4; ++i) {
            float ls = 0.f, lq = 0.f;
#pragma unroll
            for (int nj = 0; nj < 4; ++nj) {
                float rv;
                if (UNWIN) rv = resf[(size_t)grow[mi][i] * 256 + cols[nj]];
                else       rv = (float)resb[(size_t)grow[mi][i] * 256 + cols[nj]];
                float v = acc[mi][nj][i] + bsv[nj] + rv;
                acc[mi][nj][i] = v;
                ls += v;
                lq += v * v;
            }
            ls += __shfl_xor(ls, 1); lq += __shfl_xor(lq, 1);
            ls += __shfl_xor(ls, 2); lq += __shfl_xor(lq, 2);
            ls += __shfl_xor(ls, 4); lq += __shfl_xor(lq, 4);
            ls += __shfl_xor(ls, 8); lq += __shfl_xor(lq, 8);
            if (lr == 0) {
                int rloc = wr * 64 + mi * 16 + lg * 4 + i;
                redS[wc][rloc] = ls;
                redQ[wc][rloc] = lq;
            }
        }
    __syncthreads();

#pragma unroll
    for (int mi = 0; mi < 4; ++mi)
#pragma unroll
        for (int i = 0; i < 4; ++i) {
            int rloc = wr * 64 + mi * 16 + lg * 4 + i;
            float S = redS[0][rloc] + redS[1][rloc] + redS[2][rloc] + redS[3][rloc];
            float Q = redQ[0][rloc] + redQ[1][rloc] + redQ[2][rloc] + redQ[3][rloc];
            float mean = S * (1.f / 256.f);
            float var = Q * (1.f / 256.f) - mean * mean;
            float rstd = rsqrtf(var + 1e-5f);
#pragma unroll
            for (int nj = 0; nj < 4; ++nj) {
                float o = (acc[mi][nj][i] - mean) * rstd * gv[nj] + bvv[nj];
                if (UNWIN) outb[(size_t)grow[mi][i] * 256 + cols[nj]] = (bf16)o;
                else       outf[(size_t)grow[mi][i] * 256 + cols[nj]] = o;
            }
        }
}

// ---------------------------------------------------------------------------
// Attention: 4 waves/block = one window's 4 heads. Direct-global fragment
// loads (K/V L2/L3-resident); only P round-trips through LDS (intra-wave,
// no barriers). obuf aliases qbuf safely (disjoint per-wave slices).
// ---------------------------------------------------------------------------
__global__ __launch_bounds__(256)
void attn_win2(const bf16* qbuf, const bf16* __restrict__ kbuf,
               const bf16* __restrict__ vtbuf, bf16* obuf)
{
    __shared__ bf16 Ps[4][64][72];
    const int tid = threadIdx.x;
    const int wv = tid >> 6, lane = tid & 63;
    const int widx = blockIdx.x, head = wv;
    const int lr = lane & 15, lg = lane >> 4;
    const bf16* qb = qbuf + (size_t)widx * 64 * 256 + head * 64;
    const bf16* kb = kbuf + (size_t)widx * 64 * 256 + head * 64;
    const bf16* vb = vtbuf + (size_t)widx * 16384 + head * 64 * 64;

    const f32x4 zero = {0.f, 0.f, 0.f, 0.f};
    f32x4 sacc[4][4];
#pragma unroll
    for (int mi = 0; mi < 4; ++mi)
#pragma unroll
        for (int nj = 0; nj < 4; ++nj) sacc[mi][nj] = zero;

#pragma unroll
    for (int k0 = 0; k0 < 64; k0 += 32) {
        bf16x8 af[4], bfr[4];
#pragma unroll
        for (int mi = 0; mi < 4; ++mi)
            af[mi] = *reinterpret_cast<const bf16x8*>(qb + (size_t)(mi * 16 + lr) * 256 + k0 + lg * 8);
#pragma unroll
        for (int nj = 0; nj < 4; ++nj)
            bfr[nj] = *reinterpret_cast<const bf16x8*>(kb + (size_t)(nj * 16 + lr) * 256 + k0 + lg * 8);
#pragma unroll
        for (int mi = 0; mi < 4; ++mi)
#pragma unroll
            for (int nj = 0; nj < 4; ++nj)
                sacc[mi][nj] = __builtin_amdgcn_mfma_f32_16x16x32_bf16(af[mi], bfr[nj], sacc[mi][nj], 0, 0, 0);
    }

    const float c = 0.125f * 1.4426950408889634f;  // log2(e)/sqrt(dh)
    float rsum[4][4];
#pragma unroll
    for (int mi = 0; mi < 4; ++mi)
#pragma unroll
        for (int i = 0; i < 4; ++i) {
            float m = fmaxf(fmaxf(sacc[mi][0][i], sacc[mi][1][i]), fmaxf(sacc[mi][2][i], sacc[mi][3][i]));
            m = fmaxf(m, __shfl_xor(m, 1));
            m = fmaxf(m, __shfl_xor(m, 2));
            m = fmaxf(m, __shfl_xor(m, 4));
            m = fmaxf(m, __shfl_xor(m, 8));
#pragma unroll
            for (int nj = 0; nj < 4; ++nj)
                sacc[mi][nj][i] = exp2f((sacc[mi][nj][i] - m) * c);
            float s = sacc[mi][0][i] + sacc[mi][1][i] + sacc[mi][2][i] + sacc[mi][3][i];
            s += __shfl_xor(s, 1);
            s += __shfl_xor(s, 2);
            s += __shfl_xor(s, 4);
            s += __shfl_xor(s, 8);
            rsum[mi][i] = s;
        }

#pragma unroll
    for (int mi = 0; mi < 4; ++mi)
#pragma unroll
        for (int nj = 0; nj < 4; ++nj)
#pragma unroll
            for (int i = 0; i < 4; ++i)
                Ps[wv][mi * 16 + lg * 4 + i][nj * 16 + lr] = (bf16)sacc[mi][nj][i];
    // intra-wave LDS dependency only; compiler orders via lgkmcnt

    f32x4 oacc[4][4];
#pragma unroll
    for (int mi = 0; mi < 4; ++mi)
#pragma unroll
        for (int nj = 0; nj < 4; ++nj) oacc[mi][nj] = zero;
#pragma unroll
    for (int k0 = 0; k0 < 64; k0 += 32) {
        bf16x8 af[4], bfr[4];
#pragma unroll
        for (int mi = 0; mi < 4; ++mi)
            af[mi] = *reinterpret_cast<const bf16x8*>(&Ps[wv][mi * 16 + lr][k0 + lg * 8]);
#pragma unroll
        for (int nj = 0; nj < 4; ++nj)
            bfr[nj] = *reinterpret_cast<const bf16x8*>(vb + (size_t)(nj * 16 + lr) * 64 + k0 + lg * 8);
#pragma unroll
        for (int mi = 0; mi < 4; ++mi)
#pragma unroll
            for (int nj = 0; nj < 4; ++nj)
                oacc[mi][nj] = __builtin_amdgcn_mfma_f32_16x16x32_bf16(af[mi], bfr[nj], oacc[mi][nj], 0, 0, 0);
    }
#pragma unroll
    for (int mi = 0; mi < 4; ++mi)
#pragma unroll
        for (int i = 0; i < 4; ++i) {
            float inv = 1.0f / rsum[mi][i];
            int row = mi * 16 + lg * 4 + i;
#pragma unroll
            for (int nj = 0; nj < 4; ++nj)
                obuf[((size_t)widx * 64 + row) * 256 + head * 64 + nj * 16 + lr] =
                    (bf16)(oacc[mi][nj][i] * inv);
        }
}

extern "C" void kernel_launch(void* const* d_in, const int* in_sizes, int n_in,
                              void* d_out, int out_size, void* d_ws, size_t ws_size,
                              hipStream_t stream)
{
    const float* feat_A       = (const float*)d_in[0];
    const float* feat_B       = (const float*)d_in[1];
    const float* pe           = (const float*)d_in[2];
    const float* qkv_w_A      = (const float*)d_in[3];
    const float* qkv_b_A      = (const float*)d_in[4];
    const float* out_w_A      = (const float*)d_in[5];
    const float* out_b_A      = (const float*)d_in[6];
    const float* norm_g_A     = (const float*)d_in[7];
    const float* norm_b_A     = (const float*)d_in[8];
    const float* ffn_norm_g_A = (const float*)d_in[9];
    const float* ffn_norm_b_A = (const float*)d_in[10];
    const float* ffn_w1_A     = (const float*)d_in[11];
    const float* ffn_b1_A     = (const float*)d_in[12];
    const float* ffn_w2_A     = (const float*)d_in[13];
    const float* ffn_b2_A     = (const float*)d_in[14];
    const float* qkv_w_B      = (const float*)d_in[15];
    const float* qkv_b_B      = (const float*)d_in[16];
    const float* out_w_B      = (const float*)d_in[17];
    const float* out_b_B      = (const float*)d_in[18];
    const float* norm_g_B     = (const float*)d_in[19];
    const float* norm_b_B     = (const float*)d_in[20];
    const float* ffn_norm_g_B = (const float*)d_in[21];
    const float* ffn_norm_b_B = (const float*)d_in[22];
    const float* ffn_w1_B     = (const float*)d_in[23];
    const float* ffn_b1_B     = (const float*)d_in[24];
    const float* ffn_w2_B     = (const float*)d_in[25];
    const float* ffn_b2_B     = (const float*)d_in[26];

    char* ws = (char*)d_ws;
    const size_t BFE = (size_t)NTOK * DMODEL;   // 16,777,216 elems
    const size_t BFB = BFE * 2;                 // 33.55 MB per bf16 buffer

    bf16* Wb = (bf16*)ws;                       // 1M bf16 = 2 MB
    size_t off = 2u * 1024 * 1024;
    bf16* awA = (bf16*)(ws + off); off += BFB;
    bf16* awB = (bf16*)(ws + off); off += BFB;
    bf16* qA  = (bf16*)(ws + off); off += BFB;
    bf16* kA  = (bf16*)(ws + off); off += BFB;
    bf16* vA  = (bf16*)(ws + off); off += BFB;
    bf16* qB  = (bf16*)(ws + off); off += BFB;
    bf16* kB  = (bf16*)(ws + off); off += BFB;
    bf16* vB  = (bf16*)(ws + off); off += BFB;
    bf16* y1A = (bf16*)(ws + off); off += BFB;
    bf16* y1B = (bf16*)(ws + off); off += BFB;
    bf16* hb  = (bf16*)(ws + off); off += BFB * 2;  // 65536 x 512

    bf16* w_qkvA = Wb + 0;
    bf16* w_outA = Wb + 196608;
    bf16* w_f1A  = Wb + 262144;
    bf16* w_f2A  = Wb + 393216;
    bf16* w_qkvB = Wb + 524288;
    bf16* w_outB = Wb + 720896;
    bf16* w_f1B  = Wb + 786432;
    bf16* w_f2B  = Wb + 917504;

    cvt8<<<1024, 256, 0, stream>>>(qkv_w_A, out_w_A, ffn_w1_A, ffn_w2_A,
                                   qkv_w_B, out_w_B, ffn_w1_B, ffn_w2_B, Wb);
    prep_win<<<dim3(8192, 2), 256, 0, stream>>>(feat_A, feat_B, pe, awA, awB);

    // pass1 (win_A): q_A = awA@wA0 ; k_B = awA@wB1 ; v_B = awA@wB2
    gemm_qkv2<<<3072, 256, 0, stream>>>(awA,
                                        w_qkvA, w_qkvB + 65536, w_qkvB + 131072,
                                        qkv_b_A, qkv_b_B + 256, qkv_b_B + 512,
                                        qA, kB, vB);
    // pass2 (win_B): q_B = awB@wB0 ; k_A = awB@wA1 ; v_A = awB@wA2
    gemm_qkv2<<<3072, 256, 0, stream>>>(awB,
                                        w_qkvB, w_qkvA + 65536, w_qkvA + 131072,
                                        qkv_b_B, qkv_b_A + 256, qkv_b_A + 512,
                                        qB, kA, vA);

    attn_win2<<<1024, 256, 0, stream>>>(qA, kA, vA, qA);
    attn_win2<<<1024, 256, 0, stream>>>(qB, kB, vB, qB);

    // stream A: out-proj + LN1 (unwin) -> FFN1 -> FFN2 + LN2
    gemm_lnr<1><<<512, 512, 0, stream>>>(qA, w_outA, out_b_A, feat_A, nullptr,
                                         norm_g_A, norm_b_A, nullptr, y1A, 256);
    gemm_gelu<<<2048, 256, 0, stream>>>(y1A, w_f1A, ffn_b1_A, hb);
    gemm_lnr<0><<<512, 512, 0, stream>>>(hb, w_f2A, ffn_b2_A, nullptr, y1A,
                                         ffn_norm_g_A, ffn_norm_b_A,
                                         (float*)d_out, nullptr, 512);

    // stream B
    gemm_lnr<1><<<512, 512, 0, stream>>>(qB, w_outB, out_b_B, feat_B, nullptr,
                                         norm_g_B, norm_b_B, nullptr, y1B, 256);
    gemm_gelu<<<2048, 256, 0, stream>>>(y1B, w_f1B, ffn_b1_B, hb);
    gemm_lnr<0><<<512, 512, 0, stream>>>(hb, w_f2B, ffn_b2_B, nullptr, y1B,
                                         ffn_norm_g_B, ffn_norm_b_B,
                                         (float*)d_out + BFE, nullptr, 512);
}

// Round 5
// 498.582 us; speedup vs baseline: 1.4251x; 1.2096x over previous
//
#include <hip/hip_runtime.h>
#include <hip/hip_bf16.h>
#include <math.h>

typedef __bf16 bf16;
typedef __bf16 bf16x8 __attribute__((ext_vector_type(8)));
typedef __bf16 bf16x4 __attribute__((ext_vector_type(4)));
typedef float f32x4 __attribute__((ext_vector_type(4)));

#define NTOK 65536
#define DMODEL 256

// async global->LDS, 16B per lane; LDS dest = wave-uniform base + lane*16
#define GL16(g, l) __builtin_amdgcn_global_load_lds( \
    (const __attribute__((address_space(1))) void*)(g), \
    (__attribute__((address_space(3))) void*)(l), 16, 0, 0)

// window-order token m -> global token g (the _reverse mapping)
__device__ __forceinline__ int unwin_idx(int m) {
    int widx = m >> 6, t = m & 63;
    int b = widx >> 6, wl = widx & 63;
    return (b << 12) | (((wl >> 3) * 8 + (t >> 3)) << 6) | ((wl & 7) * 8 + (t & 7));
}

__device__ __forceinline__ float gelu_fast(float x) {
    float z = 0.7978845608f * (x + 0.044715f * x * x * x);
    float e = __expf(2.f * z);
    float t = (e - 1.f) / (e + 1.f);
    return 0.5f * x * (1.f + t);
}

// ---------------------------------------------------------------------------
// prep: aw[m][c] = bf16(feat[unwin(m)][c] + pe[m&63][c]); grid (8192, 2)
// ---------------------------------------------------------------------------
__global__ __launch_bounds__(256)
void prep_win(const float* __restrict__ fA, const float* __restrict__ fB,
              const float* __restrict__ pe,
              bf16* __restrict__ awA, bf16* __restrict__ awB)
{
    const float* f = blockIdx.y ? fB : fA;
    bf16* aw = blockIdx.y ? awB : awA;
    int m = blockIdx.x * 8 + (threadIdx.x >> 5);
    int c = (threadIdx.x & 31) * 8;
    int g = unwin_idx(m), t = m & 63;
    const float4* fs = reinterpret_cast<const float4*>(f + (size_t)g * 256 + c);
    const float4* ps = reinterpret_cast<const float4*>(pe + t * 256 + c);
    float4 a0 = fs[0], a1 = fs[1], p0 = ps[0], p1 = ps[1];
    bf16x8 o;
    o[0] = (bf16)(a0.x + p0.x); o[1] = (bf16)(a0.y + p0.y);
    o[2] = (bf16)(a0.z + p0.z); o[3] = (bf16)(a0.w + p0.w);
    o[4] = (bf16)(a1.x + p1.x); o[5] = (bf16)(a1.y + p1.y);
    o[6] = (bf16)(a1.z + p1.z); o[7] = (bf16)(a1.w + p1.w);
    *reinterpret_cast<bf16x8*>(aw + (size_t)m * 256 + c) = o;
}

// ---------------------------------------------------------------------------
// weight convert: all 8 fp32 weight arrays -> one bf16 pool (fixed layout)
// ---------------------------------------------------------------------------
__global__ __launch_bounds__(256)
void cvt8(const float* __restrict__ s0, const float* __restrict__ s1,
          const float* __restrict__ s2, const float* __restrict__ s3,
          const float* __restrict__ s4, const float* __restrict__ s5,
          const float* __restrict__ s6, const float* __restrict__ s7,
          bf16* __restrict__ d)
{
    int idx = (blockIdx.x * 256 + threadIdx.x) * 4;
    const float* s; int off;
    if      (idx < 196608) { s = s0; off = 0; }
    else if (idx < 262144) { s = s1; off = 196608; }
    else if (idx < 393216) { s = s2; off = 262144; }
    else if (idx < 524288) { s = s3; off = 393216; }
    else if (idx < 720896) { s = s4; off = 524288; }
    else if (idx < 786432) { s = s5; off = 720896; }
    else if (idx < 917504) { s = s6; off = 786432; }
    else                   { s = s7; off = 917504; }
    float4 v = *reinterpret_cast<const float4*>(s + (idx - off));
    bf16x4 o; o[0] = (bf16)v.x; o[1] = (bf16)v.y; o[2] = (bf16)v.z; o[3] = (bf16)v.w;
    *reinterpret_cast<bf16x4*>(d + idx) = o;
}

// ---------------------------------------------------------------------------
// Merged QKV GEMM, both passes. grid 6144 = 8 XCD chunks of 768.
// logical L -> mt (0..1023: pass*512+mb), nb (0..5: seg*2 + n-half).
// 2-phase double-buffered LDS, 128x128 tile, 4 waves.
// pass0 (A=awA): q_A|k_B|v_B ; pass1 (A=awB): q_B|k_A|v_A. v written win-T.
// ---------------------------------------------------------------------------
__global__ __launch_bounds__(256, 4)
void gemm_qkv2(const bf16* __restrict__ awA, const bf16* __restrict__ awB,
               const bf16* __restrict__ wA, const bf16* __restrict__ wB,
               const float* __restrict__ bA, const float* __restrict__ bB,
               bf16* __restrict__ qA, bf16* __restrict__ kA, bf16* __restrict__ vA,
               bf16* __restrict__ qB, bf16* __restrict__ kB, bf16* __restrict__ vB)
{
    __shared__ bf16 As[2][4096];
    __shared__ bf16 Bs[2][4096];
    const int tid = threadIdx.x;
    const int bx = blockIdx.x;
    const int xcd = bx & 7, slot = bx >> 3;
    const int L = xcd * 768 + slot;           // XCD-chunked: same-A blocks colocate
    const int mt = L / 6, nb = L - mt * 6;
    const int pass = mt >> 9, mb = mt & 511;
    const int seg = nb >> 1, nl0 = (nb & 1) * 128;
    const int m0 = mb * 128;

    const bf16* A = pass ? awB : awA;
    const bf16* Wf = (seg == 0) ? (pass ? wB : wA) : (pass ? wA : wB);
    const float* Bf = (seg == 0) ? (pass ? bB : bA) : (pass ? bA : bB);
    const bf16* W = Wf + (size_t)seg * 65536;
    const float* bia = Bf + seg * 256;
    bf16* qout = pass ? qB : qA;
    bf16* kout = pass ? kA : kB;
    bf16* vout = pass ? vA : vB;

    const int lane = tid & 63, w = tid >> 6;
    const int wr = w >> 1, wc = w & 1;
    const int lr = lane & 15, lg = lane >> 4;
    const int srow = tid >> 2, scol = (tid & 3) * 8;

    const bf16* Ag = A + (size_t)(m0 + srow) * 256 + scol;
    const bf16* Bg = W + (size_t)(nl0 + srow) * 256 + scol;

    f32x4 acc[4][4];
    const f32x4 zero = {0.f, 0.f, 0.f, 0.f};
#pragma unroll
    for (int mi = 0; mi < 4; ++mi)
#pragma unroll
        for (int nj = 0; nj < 4; ++nj) acc[mi][nj] = zero;

    auto stage = [&](int buf, int k0) {
        GL16(Ag + k0, &As[buf][tid * 8]);
        GL16(Ag + 64 * 256 + k0, &As[buf][2048 + tid * 8]);
        GL16(Bg + k0, &Bs[buf][tid * 8]);
        GL16(Bg + 64 * 256 + k0, &Bs[buf][2048 + tid * 8]);
    };
    auto compute = [&](int buf) {
        bf16x8 af[4], bfr[4];
#pragma unroll
        for (int mi = 0; mi < 4; ++mi)
            af[mi] = *reinterpret_cast<const bf16x8*>(&As[buf][(wr * 64 + mi * 16 + lr) * 32 + lg * 8]);
#pragma unroll
        for (int nj = 0; nj < 4; ++nj)
            bfr[nj] = *reinterpret_cast<const bf16x8*>(&Bs[buf][(wc * 64 + nj * 16 + lr) * 32 + lg * 8]);
#pragma unroll
        for (int mi = 0; mi < 4; ++mi)
#pragma unroll
            for (int nj = 0; nj < 4; ++nj)
                acc[mi][nj] = __builtin_amdgcn_mfma_f32_16x16x32_bf16(af[mi], bfr[nj], acc[mi][nj], 0, 0, 0);
    };

    stage(0, 0);
    __syncthreads();
#pragma unroll
    for (int t = 0; t < 7; ++t) {
        stage((t + 1) & 1, (t + 1) * 32);   // prefetch next under compute
        compute(t & 1);
        __syncthreads();
    }
    compute(1);

    if (seg == 2) {
        const int widx = mb * 2 + wr;
#pragma unroll
        for (int nj = 0; nj < 4; ++nj) {
            int cl = nl0 + wc * 64 + nj * 16 + lr;
            float bv = bia[cl];
#pragma unroll
            for (int mi = 0; mi < 4; ++mi) {
                bf16x4 o;
#pragma unroll
                for (int i = 0; i < 4; ++i) o[i] = (bf16)(acc[mi][nj][i] + bv);
                *reinterpret_cast<bf16x4*>(vout + ((size_t)widx * 256 + cl) * 64 + mi * 16 + lg * 4) = o;
            }
        }
    } else {
        bf16* out = (seg == 0) ? qout : kout;
#pragma unroll
        for (int nj = 0; nj < 4; ++nj) {
            int cl = nl0 + wc * 64 + nj * 16 + lr;
            float bv = bia[cl];
#pragma unroll
            for (int mi = 0; mi < 4; ++mi)
#pragma unroll
                for (int i = 0; i < 4; ++i) {
                    int row = m0 + wr * 64 + mi * 16 + lg * 4 + i;
                    out[(size_t)row * 256 + cl] = (bf16)(acc[mi][nj][i] + bv);
                }
        }
    }
}

// ---------------------------------------------------------------------------
// Merged FFN1 (both streams): C = gelu(A@W^T + b). grid 4096 = 8 chunks of 512.
// ---------------------------------------------------------------------------
__global__ __launch_bounds__(256, 4)
void gemm_gelu(const bf16* __restrict__ y1A, const bf16* __restrict__ y1B,
               const bf16* __restrict__ wA, const bf16* __restrict__ wB,
               const float* __restrict__ bA, const float* __restrict__ bB,
               bf16* __restrict__ hbA, bf16* __restrict__ hbB)
{
    __shared__ bf16 As[2][4096];
    __shared__ bf16 Bs[2][4096];
    const int tid = threadIdx.x;
    const int bx = blockIdx.x;
    const int xcd = bx & 7, slot = bx >> 3;
    const int L = xcd * 512 + slot;
    const int mt = L >> 2, nb = L & 3;
    const int str = mt >> 9, mb = mt & 511;
    const int m0 = mb * 128, n0 = nb * 128;

    const bf16* A = str ? y1B : y1A;
    const bf16* W = str ? wB : wA;
    const float* bia = str ? bB : bA;
    bf16* C = str ? hbB : hbA;

    const int lane = tid & 63, w = tid >> 6;
    const int wr = w >> 1, wc = w & 1;
    const int lr = lane & 15, lg = lane >> 4;
    const int srow = tid >> 2, scol = (tid & 3) * 8;

    const bf16* Ag = A + (size_t)(m0 + srow) * 256 + scol;
    const bf16* Bg = W + (size_t)(n0 + srow) * 256 + scol;

    f32x4 acc[4][4];
    const f32x4 zero = {0.f, 0.f, 0.f, 0.f};
#pragma unroll
    for (int mi = 0; mi < 4; ++mi)
#pragma unroll
        for (int nj = 0; nj < 4; ++nj) acc[mi][nj] = zero;

    auto stage = [&](int buf, int k0) {
        GL16(Ag + k0, &As[buf][tid * 8]);
        GL16(Ag + 64 * 256 + k0, &As[buf][2048 + tid * 8]);
        GL16(Bg + k0, &Bs[buf][tid * 8]);
        GL16(Bg + 64 * 256 + k0, &Bs[buf][2048 + tid * 8]);
    };
    auto compute = [&](int buf) {
        bf16x8 af[4], bfr[4];
#pragma unroll
        for (int mi = 0; mi < 4; ++mi)
            af[mi] = *reinterpret_cast<const bf16x8*>(&As[buf][(wr * 64 + mi * 16 + lr) * 32 + lg * 8]);
#pragma unroll
        for (int nj = 0; nj < 4; ++nj)
            bfr[nj] = *reinterpret_cast<const bf16x8*>(&Bs[buf][(wc * 64 + nj * 16 + lr) * 32 + lg * 8]);
#pragma unroll
        for (int mi = 0; mi < 4; ++mi)
#pragma unroll
            for (int nj = 0; nj < 4; ++nj)
                acc[mi][nj] = __builtin_amdgcn_mfma_f32_16x16x32_bf16(af[mi], bfr[nj], acc[mi][nj], 0, 0, 0);
    };

    stage(0, 0);
    __syncthreads();
#pragma unroll
    for (int t = 0; t < 7; ++t) {
        stage((t + 1) & 1, (t + 1) * 32);
        compute(t & 1);
        __syncthreads();
    }
    compute(1);

#pragma unroll
    for (int nj = 0; nj < 4; ++nj) {
        int col = n0 + wc * 64 + nj * 16 + lr;
        float bv = bia[col];
#pragma unroll
        for (int mi = 0; mi < 4; ++mi)
#pragma unroll
            for (int i = 0; i < 4; ++i) {
                int row = m0 + wr * 64 + mi * 16 + lg * 4 + i;
                C[(size_t)row * 512 + col] = (bf16)gelu_fast(acc[mi][nj][i] + bv);
            }
    }
}

// ---------------------------------------------------------------------------
// Merged GEMM + residual + LN (both streams). 128x256 tile, 8 waves, 2-phase.
// UNWIN=1: res = fp32 feat (unwin rows), out = bf16. UNWIN=0: res=bf16, out=fp32.
// grid 1024 (512 per stream).
// ---------------------------------------------------------------------------
template<int UNWIN>
__global__ __launch_bounds__(512, 4)
void gemm_lnr(const bf16* __restrict__ A0, const bf16* __restrict__ A1,
              const bf16* __restrict__ W0, const bf16* __restrict__ W1,
              const float* __restrict__ bias0, const float* __restrict__ bias1,
              const float* __restrict__ rf0, const float* __restrict__ rf1,
              const bf16* __restrict__ rb0, const bf16* __restrict__ rb1,
              const float* __restrict__ g0, const float* __restrict__ g1,
              const float* __restrict__ be0, const float* __restrict__ be1,
              float* __restrict__ of0, float* __restrict__ of1,
              bf16* __restrict__ ob0, bf16* __restrict__ ob1, int K)
{
    __shared__ bf16 As[2][4096];
    __shared__ bf16 Bs[2][8192];
    __shared__ float redS[4][128];
    __shared__ float redQ[4][128];
    const int tid = threadIdx.x;
    const int bx = blockIdx.x;
    const int str = bx >> 9, mb = bx & 511;
    const int m0 = mb * 128;

    const bf16* A = str ? A1 : A0;
    const bf16* W = str ? W1 : W0;
    const float* bias = str ? bias1 : bias0;
    const float* resf = str ? rf1 : rf0;
    const bf16* resb = str ? rb1 : rb0;
    const float* gamma = str ? g1 : g0;
    const float* beta = str ? be1 : be0;
    float* outf = str ? of1 : of0;
    bf16* outb = str ? ob1 : ob0;

    const int lane = tid & 63, w = tid >> 6;
    const int wr = w >> 2, wc = w & 3;
    const int lr = lane & 15, lg = lane >> 4;
    const int srow = tid >> 2, scol = (tid & 3) * 8;

    const bf16* Ag = A + (size_t)(m0 + srow) * K + scol;
    const bf16* Bg0 = W + (size_t)srow * K + scol;
    const bf16* Bg1 = W + (size_t)(128 + srow) * K + scol;

    f32x4 acc[4][4];
    const f32x4 zero = {0.f, 0.f, 0.f, 0.f};
#pragma unroll
    for (int mi = 0; mi < 4; ++mi)
#pragma unroll
        for (int nj = 0; nj < 4; ++nj) acc[mi][nj] = zero;

    auto stage = [&](int buf, int k0) {
        GL16(Ag + k0, &As[buf][tid * 8]);
        GL16(Bg0 + k0, &Bs[buf][tid * 8]);
        GL16(Bg1 + k0, &Bs[buf][4096 + tid * 8]);
    };
    auto compute = [&](int buf) {
        bf16x8 af[4], bfr[4];
#pragma unroll
        for (int mi = 0; mi < 4; ++mi)
            af[mi] = *reinterpret_cast<const bf16x8*>(&As[buf][(wr * 64 + mi * 16 + lr) * 32 + lg * 8]);
#pragma unroll
        for (int nj = 0; nj < 4; ++nj)
            bfr[nj] = *reinterpret_cast<const bf16x8*>(&Bs[buf][(wc * 64 + nj * 16 + lr) * 32 + lg * 8]);
#pragma unroll
        for (int mi = 0; mi < 4; ++mi)
#pragma unroll
            for (int nj = 0; nj < 4; ++nj)
                acc[mi][nj] = __builtin_amdgcn_mfma_f32_16x16x32_bf16(af[mi], bfr[nj], acc[mi][nj], 0, 0, 0);
    };

    const int NT = K >> 5;
    stage(0, 0);
    __syncthreads();
    for (int t = 0; t < NT - 1; ++t) {
        stage((t + 1) & 1, (t + 1) * 32);
        compute(t & 1);
        __syncthreads();
    }
    compute((NT - 1) & 1);

    float bsv[4], gv[4], bvv[4];
    int cols[4];
#pragma unroll
    for (int nj = 0; nj < 4; ++nj) {
        cols[nj] = wc * 64 + nj * 16 + lr;
        bsv[nj] = bias[cols[nj]];
        gv[nj] = gamma[cols[nj]];
        bvv[nj] = beta[cols[nj]];
    }
    int grow[4][4];
#pragma unroll
    for (int mi = 0; mi < 4; ++mi)
#pragma unroll
        for (int i = 0; i < 4; ++i) {
            int m = m0 + wr * 64 + mi * 16 + lg * 4 + i;
            grow[mi][i] = UNWIN ? unwin_idx(m) : m;
        }

#pragma unroll
    for (int mi = 0; mi < 4; ++mi)
#pragma unroll
        for (int i = 0; i < 4; ++i) {
            float ls = 0.f, lq = 0.f;
#pragma unroll
            for (int nj = 0; nj < 4; ++nj) {
                float rv;
                if (UNWIN) rv = resf[(size_t)grow[mi][i] * 256 + cols[nj]];
                else       rv = (float)resb[(size_t)grow[mi][i] * 256 + cols[nj]];
                float v = acc[mi][nj][i] + bsv[nj] + rv;
                acc[mi][nj][i] = v;
                ls += v;
                lq += v * v;
            }
            ls += __shfl_xor(ls, 1); lq += __shfl_xor(lq, 1);
            ls += __shfl_xor(ls, 2); lq += __shfl_xor(lq, 2);
            ls += __shfl_xor(ls, 4); lq += __shfl_xor(lq, 4);
            ls += __shfl_xor(ls, 8); lq += __shfl_xor(lq, 8);
            if (lr == 0) {
                int rloc = wr * 64 + mi * 16 + lg * 4 + i;
                redS[wc][rloc] = ls;
                redQ[wc][rloc] = lq;
            }
        }
    __syncthreads();

#pragma unroll
    for (int mi = 0; mi < 4; ++mi)
#pragma unroll
        for (int i = 0; i < 4; ++i) {
            int rloc = wr * 64 + mi * 16 + lg * 4 + i;
            float S = redS[0][rloc] + redS[1][rloc] + redS[2][rloc] + redS[3][rloc];
            float Q = redQ[0][rloc] + redQ[1][rloc] + redQ[2][rloc] + redQ[3][rloc];
            float mean = S * (1.f / 256.f);
            float var = Q * (1.f / 256.f) - mean * mean;
            float rstd = rsqrtf(var + 1e-5f);
#pragma unroll
            for (int nj = 0; nj < 4; ++nj) {
                float o = (acc[mi][nj][i] - mean) * rstd * gv[nj] + bvv[nj];
                if (UNWIN) outb[(size_t)grow[mi][i] * 256 + cols[nj]] = (bf16)o;
                else       outf[(size_t)grow[mi][i] * 256 + cols[nj]] = o;
            }
        }
}

// ---------------------------------------------------------------------------
// Merged attention (both streams). 4 waves/block = one window's 4 heads.
// Direct-global fragment loads; P via LDS intra-wave. obuf aliases qbuf.
// grid 2048 (1024 per stream).
// ---------------------------------------------------------------------------
__global__ __launch_bounds__(256)
void attn_win2(const bf16* qA, const bf16* __restrict__ kA,
               const bf16* __restrict__ vA,
               const bf16* qB, const bf16* __restrict__ kB,
               const bf16* __restrict__ vB)
{
    __shared__ bf16 Ps[4][64][72];
    const int tid = threadIdx.x;
    const int wv = tid >> 6, lane = tid & 63;
    const int str = blockIdx.x >> 10, widx = blockIdx.x & 1023, head = wv;
    const int lr = lane & 15, lg = lane >> 4;
    const bf16* qbuf = str ? qB : qA;
    const bf16* kbuf = str ? kB : kA;
    const bf16* vtbuf = str ? vB : vA;
    bf16* obuf = const_cast<bf16*>(qbuf);
    const bf16* qb = qbuf + (size_t)widx * 64 * 256 + head * 64;
    const bf16* kb = kbuf + (size_t)widx * 64 * 256 + head * 64;
    const bf16* vb = vtbuf + (size_t)widx * 16384 + head * 64 * 64;

    const f32x4 zero = {0.f, 0.f, 0.f, 0.f};
    f32x4 sacc[4][4];
#pragma unroll
    for (int mi = 0; mi < 4; ++mi)
#pragma unroll
        for (int nj = 0; nj < 4; ++nj) sacc[mi][nj] = zero;

#pragma unroll
    for (int k0 = 0; k0 < 64; k0 += 32) {
        bf16x8 af[4], bfr[4];
#pragma unroll
        for (int mi = 0; mi < 4; ++mi)
            af[mi] = *reinterpret_cast<const bf16x8*>(qb + (size_t)(mi * 16 + lr) * 256 + k0 + lg * 8);
#pragma unroll
        for (int nj = 0; nj < 4; ++nj)
            bfr[nj] = *reinterpret_cast<const bf16x8*>(kb + (size_t)(nj * 16 + lr) * 256 + k0 + lg * 8);
#pragma unroll
        for (int mi = 0; mi < 4; ++mi)
#pragma unroll
            for (int nj = 0; nj < 4; ++nj)
                sacc[mi][nj] = __builtin_amdgcn_mfma_f32_16x16x32_bf16(af[mi], bfr[nj], sacc[mi][nj], 0, 0, 0);
    }

    const float c = 0.125f * 1.4426950408889634f;  // log2(e)/sqrt(dh)
    float rsum[4][4];
#pragma unroll
    for (int mi = 0; mi < 4; ++mi)
#pragma unroll
        for (int i = 0; i < 4; ++i) {
            float m = fmaxf(fmaxf(sacc[mi][0][i], sacc[mi][1][i]), fmaxf(sacc[mi][2][i], sacc[mi][3][i]));
            m = fmaxf(m, __shfl_xor(m, 1));
            m = fmaxf(m, __shfl_xor(m, 2));
            m = fmaxf(m, __shfl_xor(m, 4));
            m = fmaxf(m, __shfl_xor(m, 8));
#pragma unroll
            for (int nj = 0; nj < 4; ++nj)
                sacc[mi][nj][i] = exp2f((sacc[mi][nj][i] - m) * c);
            float s = sacc[mi][0][i] + sacc[mi][1][i] + sacc[mi][2][i] + sacc[mi][3][i];
            s += __shfl_xor(s, 1);
            s += __shfl_xor(s, 2);
            s += __shfl_xor(s, 4);
            s += __shfl_xor(s, 8);
            rsum[mi][i] = s;
        }

#pragma unroll
    for (int mi = 0; mi < 4; ++mi)
#pragma unroll
        for (int nj = 0; nj < 4; ++nj)
#pragma unroll
            for (int i = 0; i < 4; ++i)
                Ps[wv][mi * 16 + lg * 4 + i][nj * 16 + lr] = (bf16)sacc[mi][nj][i];

    f32x4 oacc[4][4];
#pragma unroll
    for (int mi = 0; mi < 4; ++mi)
#pragma unroll
        for (int nj = 0; nj < 4; ++nj) oacc[mi][nj] = zero;
#pragma unroll
    for (int k0 = 0; k0 < 64; k0 += 32) {
        bf16x8 af[4], bfr[4];
#pragma unroll
        for (int mi = 0; mi < 4; ++mi)
            af[mi] = *reinterpret_cast<const bf16x8*>(&Ps[wv][mi * 16 + lr][k0 + lg * 8]);
#pragma unroll
        for (int nj = 0; nj < 4; ++nj)
            bfr[nj] = *reinterpret_cast<const bf16x8*>(vb + (size_t)(nj * 16 + lr) * 64 + k0 + lg * 8);
#pragma unroll
        for (int mi = 0; mi < 4; ++mi)
#pragma unroll
            for (int nj = 0; nj < 4; ++nj)
                oacc[mi][nj] = __builtin_amdgcn_mfma_f32_16x16x32_bf16(af[mi], bfr[nj], oacc[mi][nj], 0, 0, 0);
    }
#pragma unroll
    for (int mi = 0; mi < 4; ++mi)
#pragma unroll
        for (int i = 0; i < 4; ++i) {
            float inv = 1.0f / rsum[mi][i];
            int row = mi * 16 + lg * 4 + i;
#pragma unroll
            for (int nj = 0; nj < 4; ++nj)
                obuf[((size_t)widx * 64 + row) * 256 + head * 64 + nj * 16 + lr] =
                    (bf16)(oacc[mi][nj][i] * inv);
        }
}

extern "C" void kernel_launch(void* const* d_in, const int* in_sizes, int n_in,
                              void* d_out, int out_size, void* d_ws, size_t ws_size,
                              hipStream_t stream)
{
    const float* feat_A       = (const float*)d_in[0];
    const float* feat_B       = (const float*)d_in[1];
    const float* pe           = (const float*)d_in[2];
    const float* qkv_w_A      = (const float*)d_in[3];
    const float* qkv_b_A      = (const float*)d_in[4];
    const float* out_w_A      = (const float*)d_in[5];
    const float* out_b_A      = (const float*)d_in[6];
    const float* norm_g_A     = (const float*)d_in[7];
    const float* norm_b_A     = (const float*)d_in[8];
    const float* ffn_norm_g_A = (const float*)d_in[9];
    const float* ffn_norm_b_A = (const float*)d_in[10];
    const float* ffn_w1_A     = (const float*)d_in[11];
    const float* ffn_b1_A     = (const float*)d_in[12];
    const float* ffn_w2_A     = (const float*)d_in[13];
    const float* ffn_b2_A     = (const float*)d_in[14];
    const float* qkv_w_B      = (const float*)d_in[15];
    const float* qkv_b_B      = (const float*)d_in[16];
    const float* out_w_B      = (const float*)d_in[17];
    const float* out_b_B      = (const float*)d_in[18];
    const float* norm_g_B     = (const float*)d_in[19];
    const float* norm_b_B     = (const float*)d_in[20];
    const float* ffn_norm_g_B = (const float*)d_in[21];
    const float* ffn_norm_b_B = (const float*)d_in[22];
    const float* ffn_w1_B     = (const float*)d_in[23];
    const float* ffn_b1_B     = (const float*)d_in[24];
    const float* ffn_w2_B     = (const float*)d_in[25];
    const float* ffn_b2_B     = (const float*)d_in[26];

    char* ws = (char*)d_ws;
    const size_t BFE = (size_t)NTOK * DMODEL;   // 16,777,216 elems
    const size_t BFB = BFE * 2;                 // 33.55 MB per bf16 buffer

    bf16* Wb = (bf16*)ws;                       // 1M bf16 = 2 MB
    size_t off = 2u * 1024 * 1024;
    bf16* awA = (bf16*)(ws + off); off += BFB;
    bf16* awB = (bf16*)(ws + off); off += BFB;
    bf16* qA  = (bf16*)(ws + off); off += BFB;
    bf16* kA  = (bf16*)(ws + off); off += BFB;
    bf16* vA  = (bf16*)(ws + off); off += BFB;
    bf16* qB  = (bf16*)(ws + off); off += BFB;
    bf16* kB  = (bf16*)(ws + off); off += BFB;
    bf16* vB  = (bf16*)(ws + off); off += BFB;
    // liveness-based reuse:
    bf16* hbA = awA;   // [65536][512]: spans awA+awB (dead after qkv)
    bf16* hbB = kA;    // spans kA+vA (dead after attn)
    bf16* y1A = kB;    // dead after attn
    bf16* y1B = vB;    // dead after attn

    bf16* w_qkvA = Wb + 0;
    bf16* w_outA = Wb + 196608;
    bf16* w_f1A  = Wb + 262144;
    bf16* w_f2A  = Wb + 393216;
    bf16* w_qkvB = Wb + 524288;
    bf16* w_outB = Wb + 720896;
    bf16* w_f1B  = Wb + 786432;
    bf16* w_f2B  = Wb + 917504;

    cvt8<<<1024, 256, 0, stream>>>(qkv_w_A, out_w_A, ffn_w1_A, ffn_w2_A,
                                   qkv_w_B, out_w_B, ffn_w1_B, ffn_w2_B, Wb);
    prep_win<<<dim3(8192, 2), 256, 0, stream>>>(feat_A, feat_B, pe, awA, awB);

    gemm_qkv2<<<6144, 256, 0, stream>>>(awA, awB, w_qkvA, w_qkvB,
                                        qkv_b_A, qkv_b_B,
                                        qA, kA, vA, qB, kB, vB);

    attn_win2<<<2048, 256, 0, stream>>>(qA, kA, vA, qB, kB, vB);

    // out-proj + LN1 (unwin) for both streams
    gemm_lnr<1><<<1024, 512, 0, stream>>>(qA, qB, w_outA, w_outB,
                                          out_b_A, out_b_B,
                                          feat_A, feat_B, nullptr, nullptr,
                                          norm_g_A, norm_g_B, norm_b_A, norm_b_B,
                                          nullptr, nullptr, y1A, y1B, 256);
    // FFN1 both streams
    gemm_gelu<<<4096, 256, 0, stream>>>(y1A, y1B, w_f1A, w_f1B,
                                        ffn_b1_A, ffn_b1_B, hbA, hbB);
    // FFN2 + LN2 both streams -> d_out
    gemm_lnr<0><<<1024, 512, 0, stream>>>(hbA, hbB, w_f2A, w_f2B,
                                          ffn_b2_A, ffn_b2_B,
                                          nullptr, nullptr, y1A, y1B,
                                          ffn_norm_g_A, ffn_norm_g_B,
                                          ffn_norm_b_A, ffn_norm_b_B,
                                          (float*)d_out, (float*)d_out + BFE,
                                          nullptr, nullptr, 512);
}